// Round 11
// baseline (246.901 us; speedup 1.0000x reference)
//
#include <hip/hip_runtime.h>
#include <math.h>

#define L_   4096
#define DM_  512
#define B_   4
#define H_   8
#define DK_  64
#define MTOT (B_*L_)      // 16384
#define TOPK 16
#define NPART 16          // FFT partial spectra per bh

typedef _Float16 f16x8 __attribute__((ext_vector_type(8)));
typedef float    f32x4 __attribute__((ext_vector_type(4)));

// ---------------------------------------------------------------- helpers ---
__device__ __forceinline__ float h2f(unsigned short u) {
  _Float16 h; __builtin_memcpy(&h, &u, 2); return (float)h;
}
__device__ __forceinline__ unsigned short f2h(float f) {
  _Float16 h = (_Float16)f;   // RNE
  unsigned short u; __builtin_memcpy(&u, &h, 2); return u;
}

// async 16B/lane global->LDS stage of a (NIT*64)x32 fp16 tile (row stride 512).
// LDS: linear [rows][4 chunks of 16B]. Swizzle (both-sides, rule 21): LDS slot
// (row, s) holds global chunk g = s ^ ((row>>1)&3); reader fetches chunk c at
// slot s = c ^ ((row>>1)&3) -> 2 lanes per bank-quad on ds_read_b128 (free).
template<int NIT>
__device__ __forceinline__ void stage_rows32(const unsigned short* __restrict__ g,
                                             int row0, int k0,
                                             unsigned short* lds, int tid) {
  const int wave = tid >> 6;
  const int rb   = tid >> 2;                       // row within 64-row group
  const int s    = tid & 3;                        // 16B slot within 64B row
#pragma unroll
  for (int it = 0; it < NIT; ++it) {
    const int row = it * 64 + rb;
    const int gch = (s ^ ((row >> 1) & 3)) * 8;    // pre-swizzled source chunk
    const unsigned short* gp = g + (size_t)(row0 + row) * 512 + k0 + gch;
    unsigned short* lp = lds + (size_t)(it * 256 + wave * 64) * 8;  // wave-uniform base
    __builtin_amdgcn_global_load_lds(
        (const __attribute__((address_space(1))) unsigned int*)gp,
        (__attribute__((address_space(3))) unsigned int*)lp, 16, 0, 0);
  }
}

// 128x64 fp16 tile variant (row stride 512), swizzle ((row)&7) over 8 chunks.
// Used by o_gemm (round-8 proven BK=64 structure).
__device__ __forceinline__ void stage_tile64(const unsigned short* __restrict__ g,
                                             int row0, int k0,
                                             unsigned short* lds, int tid) {
  const int wave = tid >> 6;
  const int rb   = tid >> 3;                       // row within 32-row group
  const int gch  = ((tid & 7) ^ (rb & 7)) * 8;     // pre-swizzled source chunk
#pragma unroll
  for (int it = 0; it < 4; ++it) {
    const int row = it * 32 + rb;
    const unsigned short* gp = g + (size_t)(row0 + row) * 512 + k0 + gch;
    unsigned short* lp = lds + (size_t)(it * 256 + wave * 64) * 8;  // wave-uniform base
    __builtin_amdgcn_global_load_lds(
        (const __attribute__((address_space(1))) unsigned int*)gp,
        (__attribute__((address_space(3))) unsigned int*)lp, 16, 0, 0);
  }
}

// =============== fused QKV GEMM: [Q|K|V] = x @ [Wq|Wk|Wv]^T + b =============
// M=16384, N=1536, K=512. 256x128 block tile, 4 waves, 128x64 PER WAVE.
// Rationale: every latency fix (XCD-L2 r8, occupancy r10, counted-vmcnt r10)
// verified its counter-mechanism without moving time -> qkv is LDS-READ-BW
// bound. 64x64/wave = 32 FLOP per LDS byte (ceiling ~30% MfmaUtil, measured
// 21-23% everywhere); 128x64/wave = 43.7 FLOP/B (12 frag reads per 32 MFMA).
// 2-phase dbuf BK=32 (proven r8 schedule), 48 KB LDS, acc[8][4]=128 VGPR,
// launch_bounds(256,2) caps VGPR at 256 -> 2 blocks/CU.
// XCD chunk: XCD k owns m-tiles [8k,8k+8) x 12 n (2 MB x + 1.5 MB W in L2).
// seg 0 -> Qh fp16 [b][h][d][t]; seg 1 -> Kh; seg 2 -> Vv [b][h][t][d].
__global__ __launch_bounds__(256, 2)
void qkv_gemm(const unsigned short* __restrict__ xh,
              const unsigned short* __restrict__ Wh,
              const float* __restrict__ bq, const float* __restrict__ bk,
              const float* __restrict__ bv,
              unsigned short* __restrict__ Qh, unsigned short* __restrict__ Kh,
              unsigned short* __restrict__ Vv)
{
  __shared__ __attribute__((aligned(16))) unsigned short Ab[2][256 * 32];
  __shared__ __attribute__((aligned(16))) unsigned short Bb[2][128 * 32];

  const int tid  = threadIdx.x;
  const int lane = tid & 63, wave = tid >> 6;
  const int bid = blockIdx.x;            // 0..767
  const int jj = bid >> 3, k8 = bid & 7; // XCD chunk
  const int mi = k8 * 8 + jj / 12, ni = jj % 12;
  const int m0 = mi * 256, n0 = ni * 128;
  const int wm = (wave >> 1) * 128, wn = (wave & 1) * 64;
  const int fr = lane & 15, fq = lane >> 4;

  f32x4 acc[8][4];
#pragma unroll
  for (int i = 0; i < 8; i++)
#pragma unroll
    for (int j = 0; j < 4; j++) acc[i][j] = (f32x4){0.f, 0.f, 0.f, 0.f};

  stage_rows32<4>(xh, m0, 0, Ab[0], tid);
  stage_rows32<2>(Wh, n0, 0, Bb[0], tid);
  asm volatile("s_waitcnt vmcnt(0)" ::: "memory");
  __builtin_amdgcn_s_barrier();

  for (int t = 0; t < 16; ++t) {
    const int cur = t & 1;
    if (t < 15) {                   // issue next-tile loads (overlap compute)
      stage_rows32<4>(xh, m0, (t + 1) * 32, Ab[cur ^ 1], tid);
      stage_rows32<2>(Wh, n0, (t + 1) * 32, Bb[cur ^ 1], tid);
    }
    f16x8 ah[8], bh[4];
#pragma unroll
    for (int mt = 0; mt < 8; ++mt) {
      const int ra = wm + mt * 16 + fr;
      ah[mt] = *(const f16x8*)&Ab[cur][ra * 32 + ((fq ^ ((ra >> 1) & 3)) << 3)];
    }
#pragma unroll
    for (int nt = 0; nt < 4; ++nt) {
      const int rb2 = wn + nt * 16 + fr;
      bh[nt] = *(const f16x8*)&Bb[cur][rb2 * 32 + ((fq ^ ((rb2 >> 1) & 3)) << 3)];
    }
#pragma unroll
    for (int mt = 0; mt < 8; ++mt)
#pragma unroll
      for (int nt = 0; nt < 4; ++nt)
        acc[mt][nt] = __builtin_amdgcn_mfma_f32_16x16x32_f16(ah[mt], bh[nt], acc[mt][nt], 0, 0, 0);
    if (t < 15) {
      asm volatile("s_waitcnt vmcnt(0)" ::: "memory");  // next tile landed
      __builtin_amdgcn_s_barrier();                     // all reads of cur done
    }
  }

  const int seg = ni >> 2;                  // 0:Q 1:K 2:V (block-uniform)
  const float* bias = (seg == 0) ? bq : (seg == 1) ? bk : bv;
  const int nseg0 = seg * 512;
  unsigned short* QKdst = (seg == 0) ? Qh : Kh;

#pragma unroll
  for (int nt = 0; nt < 4; ++nt) {
    const int n  = n0 + wn + nt * 16 + fr;
    const int nl = n - nseg0;
    const float bb = bias[nl];
    const int h = nl >> 6, d = nl & 63;
#pragma unroll
    for (int mt = 0; mt < 8; ++mt) {
      const int mb = m0 + wm + mt * 16 + fq * 4;
      f32x4 a = acc[mt][nt];
      if (seg < 2) {
        const int b = mb >> 12, l0 = mb & (L_ - 1);
        ushort4 st;
        st.x = f2h(a[0] + bb); st.y = f2h(a[1] + bb);
        st.z = f2h(a[2] + bb); st.w = f2h(a[3] + bb);
        *(ushort4*)(QKdst + ((size_t)(b * H_ + h) * DK_ + d) * L_ + l0) = st;
      } else {
#pragma unroll
        for (int r = 0; r < 4; ++r) {
          int m = mb + r;
          int b = m >> 12, l = m & (L_ - 1);
          Vv[((size_t)(b * H_ + h) * L_ + l) * DK_ + d] = f2h(a[r] + bb);
        }
      }
    }
  }
}

// ====================== O GEMM: out = ctx @ Wo^T + bias =====================
// Round-8 proven structure: 128x128 tile, BK=64 2-phase dbuf, XCD-chunked.
__global__ __launch_bounds__(256)
void o_gemm(const unsigned short* __restrict__ Ah,
            const unsigned short* __restrict__ Bh,
            const float* __restrict__ bias, float* __restrict__ Cout)
{
  __shared__ __attribute__((aligned(16))) unsigned short Ab[2][128 * 64];
  __shared__ __attribute__((aligned(16))) unsigned short Bb[2][128 * 64];

  const int tid  = threadIdx.x;
  const int lane = tid & 63, wave = tid >> 6;
  const int bid = blockIdx.x;            // 0..511
  const int jj = bid >> 3, k8 = bid & 7;
  const int mi = k8 * 16 + (jj >> 2), ni = jj & 3;
  const int m0 = mi * 128, n0 = ni * 128;
  const int wm = (wave >> 1) * 64, wn = (wave & 1) * 64;
  const int fr = lane & 15, fq = lane >> 4;
  const int sw = fr & 7;

  f32x4 acc[4][4];
#pragma unroll
  for (int i = 0; i < 4; i++)
#pragma unroll
    for (int j = 0; j < 4; j++) acc[i][j] = (f32x4){0.f, 0.f, 0.f, 0.f};

  stage_tile64(Ah, m0, 0, Ab[0], tid);
  stage_tile64(Bh, n0, 0, Bb[0], tid);
  asm volatile("s_waitcnt vmcnt(0)" ::: "memory");
  __builtin_amdgcn_s_barrier();

  for (int t = 0; t < 8; ++t) {
    const int cur = t & 1;
    if (t < 7) {
      stage_tile64(Ah, m0, (t + 1) * 64, Ab[cur ^ 1], tid);
      stage_tile64(Bh, n0, (t + 1) * 64, Bb[cur ^ 1], tid);
    }
#pragma unroll
    for (int kk = 0; kk < 2; ++kk) {
      f16x8 ah[4], bh[4];
#pragma unroll
      for (int mt = 0; mt < 4; ++mt)
        ah[mt] = *(const f16x8*)&Ab[cur][(wm + mt * 16 + fr) * 64 + ((kk * 4 + fq) ^ sw) * 8];
#pragma unroll
      for (int nt = 0; nt < 4; ++nt)
        bh[nt] = *(const f16x8*)&Bb[cur][(wn + nt * 16 + fr) * 64 + ((kk * 4 + fq) ^ sw) * 8];
#pragma unroll
      for (int mt = 0; mt < 4; ++mt)
#pragma unroll
        for (int nt = 0; nt < 4; ++nt)
          acc[mt][nt] = __builtin_amdgcn_mfma_f32_16x16x32_f16(ah[mt], bh[nt], acc[mt][nt], 0, 0, 0);
    }
    if (t < 7) {
      asm volatile("s_waitcnt vmcnt(0)" ::: "memory");
      __builtin_amdgcn_s_barrier();
    }
  }

#pragma unroll
  for (int nt = 0; nt < 4; ++nt) {
    const int n = n0 + wn + nt * 16 + fr;
    const float bb = bias[n];
#pragma unroll
    for (int mt = 0; mt < 4; ++mt) {
      const int mb = m0 + wm + mt * 16 + fq * 4;
      f32x4 a = acc[mt][nt];
#pragma unroll
      for (int r = 0; r < 4; ++r) {
        int m = mb + r;
        Cout[(size_t)m * DM_ + n] = a[r] + bb;
      }
    }
  }
}

// ============== one-shot: x and all 4 weights -> fp16 (RNE) =================
// chunks: x = 2,097,152 float4; each W = 65,536 float4. total 2,359,296.
__global__ __launch_bounds__(256)
void split_all(const float* __restrict__ x,  const float* __restrict__ Wq,
               const float* __restrict__ Wk, const float* __restrict__ Wv,
               const float* __restrict__ Wo,
               unsigned short* __restrict__ xh,
               unsigned short* __restrict__ Wqkvh, unsigned short* __restrict__ Woh)
{
  int i = blockIdx.x * 256 + threadIdx.x;
  const float* src; unsigned short* dh; int off;
  if (i < 2097152) { src = x; dh = xh; off = i; }
  else {
    int j = i - 2097152; int seg = j >> 16; off = j & 65535;
    if (seg == 0)      { src = Wq; dh = Wqkvh; }
    else if (seg == 1) { src = Wk; dh = Wqkvh + 262144; }
    else if (seg == 2) { src = Wv; dh = Wqkvh + 524288; }
    else               { src = Wo; dh = Woh; }
  }
  float4 v = ((const float4*)src)[off];
  ushort4 h;
  h.x = f2h(v.x); h.y = f2h(v.y); h.z = f2h(v.z); h.w = f2h(v.w);
  ((ushort4*)dh)[off] = h;
}

// ==================== FFT: radix-16 Stockham, N=4096, 3 stages ==============
#define FPAD(a) ((a) + ((a) >> 4))
#define LDSN 4352

__device__ __forceinline__ float2 cmul(float2 a, float2 b) {
  return make_float2(a.x * b.x - a.y * b.y, a.x * b.y + a.y * b.x);
}

__device__ __forceinline__ void dft16(float2* x)
{
  const float C1 = 0.9238795325112867f, S1 = 0.3826834323650898f;
  const float C2 = 0.7071067811865476f;
  const float2 w16[16] = {
    { 1.f, 0.f}, { C1,-S1}, { C2,-C2}, { S1,-C1},
    { 0.f,-1.f}, {-S1,-C1}, {-C2,-C2}, {-C1,-S1},
    {-1.f, 0.f}, {-C1, S1}, {-C2, C2}, {-S1, C1},
    { 0.f, 1.f}, { S1, C1}, { C2, C2}, { C1, S1}};
  float2 y[16];
#pragma unroll
  for (int jj = 0; jj < 4; jj++) {
    float2 a = x[jj], b = x[jj + 4], c = x[jj + 8], d = x[jj + 12];
    float2 t0 = make_float2(a.x + c.x, a.y + c.y);
    float2 t1 = make_float2(a.x - c.x, a.y - c.y);
    float2 t2 = make_float2(b.x + d.x, b.y + d.y);
    float2 t3 = make_float2(b.x - d.x, b.y - d.y);
    float2 u0 = make_float2(t0.x + t2.x, t0.y + t2.y);
    float2 u2 = make_float2(t0.x - t2.x, t0.y - t2.y);
    float2 u1 = make_float2(t1.x + t3.y, t1.y - t3.x);
    float2 u3 = make_float2(t1.x - t3.y, t1.y + t3.x);
    y[4 * jj + 0] = u0;
    y[4 * jj + 1] = cmul(u1, w16[(jj * 1) & 15]);
    y[4 * jj + 2] = cmul(u2, w16[(jj * 2) & 15]);
    y[4 * jj + 3] = cmul(u3, w16[(jj * 3) & 15]);
  }
#pragma unroll
  for (int jj = 0; jj < 4; jj++) {
    float2 a = y[jj], b = y[jj + 4], c = y[jj + 8], d = y[jj + 12];
    float2 t0 = make_float2(a.x + c.x, a.y + c.y);
    float2 t1 = make_float2(a.x - c.x, a.y - c.y);
    float2 t2 = make_float2(b.x + d.x, b.y + d.y);
    float2 t3 = make_float2(b.x - d.x, b.y - d.y);
    x[jj + 0]  = make_float2(t0.x + t2.x, t0.y + t2.y);
    x[jj + 8]  = make_float2(t0.x - t2.x, t0.y - t2.y);
    x[jj + 4]  = make_float2(t1.x + t3.y, t1.y - t3.x);
    x[jj + 12] = make_float2(t1.x - t3.y, t1.y + t3.x);
  }
}

// stage 1 from registers: x[r] = z[j + 256r]; writes padded stage-1 output.
__device__ __forceinline__ void fft_stage1_reg(float2* x, float2* __restrict__ Ys, int j)
{
  dft16(x);
  float ang = -1.5339807878856412e-3f * (float)j;   // -2*pi/4096 * j
  float2 w; __sincosf(ang, &w.y, &w.x);
  float2 t = w;
#pragma unroll
  for (int k = 1; k < 16; k++) { x[k] = cmul(x[k], t); t = cmul(t, w); }
  float2* yp = Ys + 17 * j;                         // FPAD(16j+k) = 17j+k
#pragma unroll
  for (int k = 0; k < 16; k++) yp[k] = x[k];
}

template<int S, bool PADOUT>
__device__ __forceinline__ void fft_stage(const float2* __restrict__ Xs,
                                          float2* __restrict__ Ys, int j)
{
  float2 x[16];
#pragma unroll
  for (int r = 0; r < 16; r++) { int a = j + 256 * r; x[r] = Xs[FPAD(a)]; }
  dft16(x);
  if (S < 256) {
    int p = (S == 1) ? j : (j >> 4);
    float ang = -1.5339807878856412e-3f * (float)(p * S);
    float2 w; __sincosf(ang, &w.y, &w.x);
    float2 t = w;
#pragma unroll
    for (int k = 1; k < 16; k++) { x[k] = cmul(x[k], t); t = cmul(t, w); }
  }
  const int q = j & (S - 1);
  const int base = q + ((j - q) << 4);   // q + 16*p*S
#pragma unroll
  for (int k = 0; k < 16; k++) {
    int a = base + k * S;
    Ys[PADOUT ? FPAD(a) : a] = x[k];
  }
}

// One workgroup per (b*H+h, d-group of 4). grid (32, 16). Q,K in fp16.
// Next channel's loads are issued right after stage1 consumes x (T14 split),
// hiding HBM latency under stages 2-3 + unpack.
__global__ __launch_bounds__(256)
void fft_fwd_kernel(const unsigned short* __restrict__ Qh,
                    const unsigned short* __restrict__ Kh,
                    float* __restrict__ P)
{
  __shared__ __attribute__((aligned(16))) float2 Abuf[LDSN];
  __shared__ __attribute__((aligned(16))) float2 Bbuf[LDSN];
  const int tid = threadIdx.x;
  const int bh = blockIdx.x;      // 0..31
  const int g  = blockIdx.y;      // 0..15
  float2 accv[16];
#pragma unroll
  for (int r = 0; r < 16; r++) accv[r] = make_float2(0.f, 0.f);

  const unsigned short* qb = Qh + (size_t)bh * DK_ * L_;
  const unsigned short* kb = Kh + (size_t)bh * DK_ * L_;

  float2 x[16];
  {
    const unsigned short* q = qb + (size_t)(g * 4) * L_;
    const unsigned short* k = kb + (size_t)(g * 4) * L_;
#pragma unroll
    for (int r = 0; r < 16; r++) {
      int t = tid + 256 * r;
      x[r] = make_float2(h2f(q[t]), h2f(k[t]));   // z = q + i*k
    }
  }

  for (int dd = 0; dd < 4; dd++) {
    __syncthreads();               // prev channel's unpack reads of Abuf done
    fft_stage1_reg(x, Abuf, tid);  // consumes x
    if (dd < 3) {                  // prefetch next channel under stages 2-3
      const unsigned short* q = qb + (size_t)(g * 4 + dd + 1) * L_;
      const unsigned short* k = kb + (size_t)(g * 4 + dd + 1) * L_;
#pragma unroll
      for (int r = 0; r < 16; r++) {
        int t = tid + 256 * r;
        x[r] = make_float2(h2f(q[t]), h2f(k[t]));
      }
    }
    __syncthreads();
    fft_stage<16, true>(Abuf, Bbuf, tid);
    __syncthreads();
    fft_stage<256, false>(Bbuf, Abuf, tid);   // result in Abuf, unpadded
    __syncthreads();
#pragma unroll
    for (int r = 0; r < 16; r++) {
      int f = tid + 256 * r;
      float2 zf = Abuf[f];
      float2 zc = Abuf[(L_ - f) & (L_ - 1)];
      float qr = 0.5f * (zf.x + zc.x);       // Qf = (Z[f]+conj(Z[N-f]))/2
      float qi = 0.5f * (zf.y - zc.y);
      float kr = 0.5f * (zf.y + zc.y);       // Kf = (Z[f]-conj(Z[N-f]))/(2i)
      float ki = 0.5f * (zc.x - zf.x);
      accv[r].x += qr * kr + qi * ki;        // G = Qf * conj(Kf)
      accv[r].y += qi * kr - qr * ki;
    }
  }
  float2* Pp = (float2*)P + ((size_t)bh * NPART + g) * L_;
#pragma unroll
  for (int r = 0; r < 16; r++) Pp[tid + 256 * r] = accv[r];
}

// ====== reduce 16 partial spectra -> conjugated spectrum S (HBM stream) =====
__global__ __launch_bounds__(256)
void reduce_partials(const float* __restrict__ P, float* __restrict__ S)
{
  const int bh = blockIdx.x;
  const int c  = blockIdx.y * 256 + threadIdx.x;   // 0..2047 float4 chunks
  const float4* Pp4 = (const float4*)P + (size_t)bh * NPART * 2048 + c;
  float4 s = make_float4(0.f, 0.f, 0.f, 0.f);
#pragma unroll
  for (int g = 0; g < NPART; g++) {
    float4 v = Pp4[(size_t)g * 2048];
    s.x += v.x; s.y += v.y; s.z += v.z; s.w += v.w;
  }
  ((float4*)S)[(size_t)bh * 2048 + c] = make_float4(s.x, -s.y, s.z, -s.w);  // conj
}

// ================= fused: inverse FFT of S + top-16 + softmax ===============
// Top-16 runs FROM LDS (rule #20). __launch_bounds__(256, 1): 32 blocks /
// 70 KB LDS -> never more than 1 block/CU; full register budget avoids the
// spill knife-edge (rule #19).
__global__ __launch_bounds__(256, 1)
void fft_inv_topk_kernel(const float* __restrict__ S, float* __restrict__ w,
                         int* __restrict__ delays)
{
  __shared__ __attribute__((aligned(16))) float2 Abuf[LDSN];
  __shared__ __attribute__((aligned(16))) float2 Bbuf[LDSN];
  __shared__ float wtv[64];
  __shared__ int   wti[64];
  const int tid = threadIdx.x;
  const int lane = tid & 63, wave = tid >> 6;
  const int bh = blockIdx.x;
  const float2* Sp = (const float2*)S + (size_t)bh * L_;

  float2 x[16];
#pragma unroll
  for (int r = 0; r < 16; r++) x[r] = Sp[tid + 256 * r];
  fft_stage1_reg(x, Abuf, tid);
  __syncthreads();
  fft_stage<16, true>(Abuf, Bbuf, tid);
  __syncthreads();
  fft_stage<256, false>(Bbuf, Abuf, tid);   // result in Abuf, unpadded
  __syncthreads();

  const float scale = 1.0f / ((float)L_ * (float)DK_);

  // phase A: per-wave top-16, values read from LDS each pass, shuffle argmax.
  for (int it = 0; it < TOPK; it++) {
    float lbv = -INFINITY; int lbi = 0;
#pragma unroll
    for (int r = 0; r < 16; r++) {
      float val = Abuf[tid + 256 * r].x;
      if (val > lbv) { lbv = val; lbi = tid + 256 * r; }
    }
    float bv = lbv; int bi = lbi;
#pragma unroll
    for (int off = 32; off > 0; off >>= 1) {
      float ov = __shfl_down(bv, off, 64);
      int   oi = __shfl_down(bi, off, 64);
      if (ov > bv || (ov == bv && oi < bi)) { bv = ov; bi = oi; }
    }
    const float wv = __shfl(bv, 0, 64);
    const int   wi = __shfl(bi, 0, 64);
    if (lane == 0) {
      wtv[wave * TOPK + it] = wv * scale;
      wti[wave * TOPK + it] = wi;
      Abuf[wi].x = -INFINITY;               // disable (own wave's region only)
    }
  }
  __syncthreads();

  // phase B: wave 0 merges 4x16 candidates -> global top-16 + softmax
  if (wave == 0) {
    float cv = wtv[lane]; int ci = wti[lane];
    float topv[TOPK]; int topi[TOPK];
#pragma unroll
    for (int it = 0; it < TOPK; it++) {
      float bv = cv; int bi = ci;
#pragma unroll
      for (int off = 1; off < 64; off <<= 1) {
        float ov = __shfl_xor(bv, off, 64);
        int   oi = __shfl_xor(bi, off, 64);
        if (ov > bv || (ov == bv && oi < bi)) { bv = ov; bi = oi; }
      }
      topv[it] = bv; topi[it] = bi;         // all lanes hold the winner
      if (ci == bi) cv = -INFINITY;         // exactly one lane matches
    }
    if (lane == 0) {
      float mx = topv[0];
#pragma unroll
      for (int j = 1; j < TOPK; j++) mx = fmaxf(mx, topv[j]);
      float e[TOPK]; float se = 0.f;
#pragma unroll
      for (int j = 0; j < TOPK; j++) { e[j] = expf(topv[j] - mx); se += e[j]; }
      float inv = 1.0f / se;
#pragma unroll
      for (int j = 0; j < TOPK; j++) {
        w[bh * TOPK + j] = e[j] * inv;
        delays[bh * TOPK + j] = topi[j];
      }
    }
  }
}

// ============================ delay gather ==================================
// V fp16 [b][h][t][d] -> ctx fp16 (RNE) [b][t][h*64+d]
// Flat grid 4096, XCD-affine: xcd = id&7 handles bh in [4*xcd, 4*xcd+4), so
// each XCD's V working set (~2 MB/bh) stays L2-resident across its blocks.
// 16B loads (f16x8), 32 t-rows per block.
__global__ __launch_bounds__(256)
void gather_kernel(const unsigned short* __restrict__ V, const float* __restrict__ w,
                   const int* __restrict__ delays, unsigned short* __restrict__ ctxh)
{
  const int id  = blockIdx.x;          // 0..4095
  const int xcd = id & 7;
  const int j   = id >> 3;             // 0..511
  const int bh  = xcd * 4 + (j >> 7);  // 4 bh per XCD, sequential within
  const int tb  = j & 127;             // t-block of 32 rows
  const int b = bh >> 3, h = bh & 7;
  __shared__ float ws[TOPK];
  __shared__ int   dls[TOPK];
  const int tid = threadIdx.x;
  if (tid < TOPK) { ws[tid] = w[bh * TOPK + tid]; dls[tid] = delays[bh * TOPK + tid]; }
  __syncthreads();
  const int t  = tb * 32 + (tid >> 3);
  const int d8 = (tid & 7) * 8;
  const unsigned short* Vh = V + (size_t)bh * L_ * DK_;
  float acc[8];
#pragma unroll
  for (int e = 0; e < 8; e++) acc[e] = 0.f;
#pragma unroll
  for (int jj = 0; jj < TOPK; jj++) {
    int row = (t - dls[jj]) & (L_ - 1);
    f16x8 vv = *(const f16x8*)(Vh + (size_t)row * DK_ + d8);
    float wj = ws[jj];
#pragma unroll
    for (int e = 0; e < 8; e++) acc[e] += wj * (float)vv[e];
  }
  f16x8 hv;
#pragma unroll
  for (int e = 0; e < 8; e++) hv[e] = (_Float16)acc[e];
  *(f16x8*)(ctxh + ((size_t)(b * L_ + t) * DM_) + h * DK_ + d8) = hv;
}

// ============================ launch ========================================
extern "C" void kernel_launch(void* const* d_in, const int* in_sizes, int n_in,
                              void* d_out, int out_size, void* d_ws, size_t ws_size,
                              hipStream_t stream)
{
  const float* x  = (const float*)d_in[0];
  const float* Wq = (const float*)d_in[1];
  const float* bq = (const float*)d_in[2];
  const float* Wk = (const float*)d_in[3];
  const float* bk = (const float*)d_in[4];
  const float* Wv = (const float*)d_in[5];
  const float* bv = (const float*)d_in[6];
  const float* Wo = (const float*)d_in[7];
  const float* bo = (const float*)d_in[8];
  float* out = (float*)d_out;
  float* ws  = (float*)d_ws;

  // workspace (float offsets).
  // region0 [0, 8388608): xh fp16 (split..qkv), then P (fft partials, 16 MB),
  //                       then ctxh fp16 (gather..o_gemm)
  unsigned short* xh = (unsigned short*)ws;                 // 8.4M fp16 (16 MB)
  float* P  = ws;                                           // 32*16*4096*2 f (16 MB)
  unsigned short* ctxh = (unsigned short*)ws;               // 8.4M fp16
  unsigned short* Qh = (unsigned short*)(ws + 8388608);     // 8.4M fp16 [b][h][d][t]
  unsigned short* Kh = (unsigned short*)(ws + 12582912);    // 8.4M fp16 [b][h][d][t]
  unsigned short* Vv = (unsigned short*)(ws + 16777216);    // 8.4M fp16 [b][h][t][d]
  unsigned short* Wqkvh = (unsigned short*)(ws + 20971520); // 786,432 fp16
  unsigned short* Woh   = (unsigned short*)(ws + 21364736); // 262,144 fp16
  float* wbuf = ws + 21495808;                              // 512
  int*   dbuf = (int*)(ws + 21496320);                      // 512
  float* S    = ws + 21496832;                              // 262,144 f (1 MB)

  split_all<<<9216, 256, 0, stream>>>(x, Wq, Wk, Wv, Wo, xh, Wqkvh, Woh);

  qkv_gemm<<<768, 256, 0, stream>>>(xh, Wqkvh, bq, bk, bv, Qh, Kh, Vv);

  fft_fwd_kernel<<<dim3(32, NPART), 256, 0, stream>>>(Qh, Kh, P);
  reduce_partials<<<dim3(32, 8), 256, 0, stream>>>(P, S);
  fft_inv_topk_kernel<<<32, 256, 0, stream>>>(S, wbuf, dbuf);
  gather_kernel<<<4096, 256, 0, stream>>>(Vv, wbuf, dbuf, ctxh);

  o_gemm<<<512, 256, 0, stream>>>(ctxh, Woh, bo, out);
}

// Round 12
// 221.597 us; speedup vs baseline: 1.1142x; 1.1142x over previous
//
#include <hip/hip_runtime.h>
#include <math.h>

#define L_   4096
#define DM_  512
#define B_   4
#define H_   8
#define DK_  64
#define MTOT (B_*L_)      // 16384
#define TOPK 16
#define NPART 16          // FFT partial spectra per bh

typedef _Float16 f16x8 __attribute__((ext_vector_type(8)));
typedef float    f32x4 __attribute__((ext_vector_type(4)));

// ---------------------------------------------------------------- helpers ---
__device__ __forceinline__ float h2f(unsigned short u) {
  _Float16 h; __builtin_memcpy(&h, &u, 2); return (float)h;
}
__device__ __forceinline__ unsigned short f2h(float f) {
  _Float16 h = (_Float16)f;   // RNE
  unsigned short u; __builtin_memcpy(&u, &h, 2); return u;
}

// async 16B/lane global->LDS stage of a 128x64 fp16 tile from a row-major
// source with row stride 512 elements. LDS layout: linear [128][64] halfs.
// Bank-conflict swizzle (both-sides, rule 21): LDS slot (row, s) holds global
// 16B-chunk g = s ^ (row&7); reader fetches chunk c at s = c ^ (row&7).
// Each 8-lane group still reads one full contiguous 128 B row (permuted).
__device__ __forceinline__ void stage_tile64(const unsigned short* __restrict__ g,
                                             int row0, int k0,
                                             unsigned short* lds, int tid) {
  const int wave = tid >> 6;
  const int rb   = tid >> 3;                       // row within 32-row group
  const int gch  = ((tid & 7) ^ (rb & 7)) * 8;     // pre-swizzled source chunk (halfs)
#pragma unroll
  for (int it = 0; it < 4; ++it) {
    const int row = it * 32 + rb;
    const unsigned short* gp = g + (size_t)(row0 + row) * 512 + k0 + gch;
    unsigned short* lp = lds + (size_t)(it * 256 + wave * 64) * 8;  // wave-uniform base
    __builtin_amdgcn_global_load_lds(
        (const __attribute__((address_space(1))) unsigned int*)gp,
        (__attribute__((address_space(3))) unsigned int*)lp, 16, 0, 0);
  }
}

// =============== fused QKV GEMM: [Q|K|V] = x @ [Wq|Wk|Wv]^T + b =============
// M=16384, N=1536 (3 segs of 512), K=512. 128x128 tile, BK=64, 4 waves.
// 2-phase double-buffer (best measured: 42-44 us): stage(t+1) issued BEFORE
// compute(t); one vmcnt(0)+barrier per K-iter. 64 KB LDS -> 2 blocks/CU.
// Session evidence: depth-2 (r6/r10), bigger wave tile (r11) all lose to
// this structure's TLP; XCD-chunk swizzle cut FETCH 30.8->20.7 MB (kept).
// seg 0 -> Qh fp16 [b][h][d][t]; seg 1 -> Kh; seg 2 -> Vv [b][h][t][d].
__global__ __launch_bounds__(256)
void qkv_gemm(const unsigned short* __restrict__ xh,
              const unsigned short* __restrict__ Wh,
              const float* __restrict__ bq, const float* __restrict__ bk,
              const float* __restrict__ bv,
              unsigned short* __restrict__ Qh, unsigned short* __restrict__ Kh,
              unsigned short* __restrict__ Vv)
{
  __shared__ __attribute__((aligned(16))) unsigned short Ab[2][128 * 64];
  __shared__ __attribute__((aligned(16))) unsigned short Bb[2][128 * 64];

  const int tid  = threadIdx.x;
  const int lane = tid & 63, wave = tid >> 6;
  const int bid = blockIdx.x;            // 0..1535
  const int jj = bid >> 3, k8 = bid & 7; // XCD chunk
  const int mi = k8 * 16 + jj / 12, ni = jj % 12;
  const int m0 = mi * 128, n0 = ni * 128;
  const int wm = (wave >> 1) * 64, wn = (wave & 1) * 64;
  const int fr = lane & 15, fq = lane >> 4;
  const int sw = fr & 7;            // row&7 for every fragment row we touch

  f32x4 acc[4][4];
#pragma unroll
  for (int i = 0; i < 4; i++)
#pragma unroll
    for (int j = 0; j < 4; j++) acc[i][j] = (f32x4){0.f, 0.f, 0.f, 0.f};

  stage_tile64(xh, m0, 0, Ab[0], tid);
  stage_tile64(Wh, n0, 0, Bb[0], tid);
  asm volatile("s_waitcnt vmcnt(0)" ::: "memory");
  __builtin_amdgcn_s_barrier();

  for (int t = 0; t < 8; ++t) {
    const int cur = t & 1;
    if (t < 7) {                    // issue next-tile loads (overlap compute)
      stage_tile64(xh, m0, (t + 1) * 64, Ab[cur ^ 1], tid);
      stage_tile64(Wh, n0, (t + 1) * 64, Bb[cur ^ 1], tid);
    }
#pragma unroll
    for (int kk = 0; kk < 2; ++kk) {
      f16x8 ah[4], bh[4];
#pragma unroll
      for (int mt = 0; mt < 4; ++mt)
        ah[mt] = *(const f16x8*)&Ab[cur][(wm + mt * 16 + fr) * 64 + ((kk * 4 + fq) ^ sw) * 8];
#pragma unroll
      for (int nt = 0; nt < 4; ++nt)
        bh[nt] = *(const f16x8*)&Bb[cur][(wn + nt * 16 + fr) * 64 + ((kk * 4 + fq) ^ sw) * 8];
#pragma unroll
      for (int mt = 0; mt < 4; ++mt)
#pragma unroll
        for (int nt = 0; nt < 4; ++nt)
          acc[mt][nt] = __builtin_amdgcn_mfma_f32_16x16x32_f16(ah[mt], bh[nt], acc[mt][nt], 0, 0, 0);
    }
    if (t < 7) {
      asm volatile("s_waitcnt vmcnt(0)" ::: "memory");  // next tile landed
      __builtin_amdgcn_s_barrier();                     // all reads of cur done
    }
  }

  const int seg = ni >> 2;                  // 0:Q 1:K 2:V (block-uniform)
  const float* bias = (seg == 0) ? bq : (seg == 1) ? bk : bv;
  const int nseg0 = seg * 512;
  unsigned short* QKdst = (seg == 0) ? Qh : Kh;

#pragma unroll
  for (int nt = 0; nt < 4; ++nt) {
    const int n  = n0 + wn + nt * 16 + fr;
    const int nl = n - nseg0;
    const float bb = bias[nl];
    const int h = nl >> 6, d = nl & 63;
#pragma unroll
    for (int mt = 0; mt < 4; ++mt) {
      const int mb = m0 + wm + mt * 16 + fq * 4;
      f32x4 a = acc[mt][nt];
      if (seg < 2) {
        const int b = mb >> 12, l0 = mb & (L_ - 1);
        ushort4 st;
        st.x = f2h(a[0] + bb); st.y = f2h(a[1] + bb);
        st.z = f2h(a[2] + bb); st.w = f2h(a[3] + bb);
        *(ushort4*)(QKdst + ((size_t)(b * H_ + h) * DK_ + d) * L_ + l0) = st;
      } else {
#pragma unroll
        for (int r = 0; r < 4; ++r) {
          int m = mb + r;
          int b = m >> 12, l = m & (L_ - 1);
          Vv[((size_t)(b * H_ + h) * L_ + l) * DK_ + d] = f2h(a[r] + bb);
        }
      }
    }
  }
}

// ====================== O GEMM: out = ctx @ Wo^T + bias =====================
// Same 2-phase BK=64 structure; XCD-chunked swizzle (16 m-tiles x 4 n per XCD).
__global__ __launch_bounds__(256)
void o_gemm(const unsigned short* __restrict__ Ah,
            const unsigned short* __restrict__ Bh,
            const float* __restrict__ bias, float* __restrict__ Cout)
{
  __shared__ __attribute__((aligned(16))) unsigned short Ab[2][128 * 64];
  __shared__ __attribute__((aligned(16))) unsigned short Bb[2][128 * 64];

  const int tid  = threadIdx.x;
  const int lane = tid & 63, wave = tid >> 6;
  const int bid = blockIdx.x;            // 0..511
  const int jj = bid >> 3, k8 = bid & 7;
  const int mi = k8 * 16 + (jj >> 2), ni = jj & 3;
  const int m0 = mi * 128, n0 = ni * 128;
  const int wm = (wave >> 1) * 64, wn = (wave & 1) * 64;
  const int fr = lane & 15, fq = lane >> 4;
  const int sw = fr & 7;

  f32x4 acc[4][4];
#pragma unroll
  for (int i = 0; i < 4; i++)
#pragma unroll
    for (int j = 0; j < 4; j++) acc[i][j] = (f32x4){0.f, 0.f, 0.f, 0.f};

  stage_tile64(Ah, m0, 0, Ab[0], tid);
  stage_tile64(Bh, n0, 0, Bb[0], tid);
  asm volatile("s_waitcnt vmcnt(0)" ::: "memory");
  __builtin_amdgcn_s_barrier();

  for (int t = 0; t < 8; ++t) {
    const int cur = t & 1;
    if (t < 7) {
      stage_tile64(Ah, m0, (t + 1) * 64, Ab[cur ^ 1], tid);
      stage_tile64(Bh, n0, (t + 1) * 64, Bb[cur ^ 1], tid);
    }
#pragma unroll
    for (int kk = 0; kk < 2; ++kk) {
      f16x8 ah[4], bh[4];
#pragma unroll
      for (int mt = 0; mt < 4; ++mt)
        ah[mt] = *(const f16x8*)&Ab[cur][(wm + mt * 16 + fr) * 64 + ((kk * 4 + fq) ^ sw) * 8];
#pragma unroll
      for (int nt = 0; nt < 4; ++nt)
        bh[nt] = *(const f16x8*)&Bb[cur][(wn + nt * 16 + fr) * 64 + ((kk * 4 + fq) ^ sw) * 8];
#pragma unroll
      for (int mt = 0; mt < 4; ++mt)
#pragma unroll
        for (int nt = 0; nt < 4; ++nt)
          acc[mt][nt] = __builtin_amdgcn_mfma_f32_16x16x32_f16(ah[mt], bh[nt], acc[mt][nt], 0, 0, 0);
    }
    if (t < 7) {
      asm volatile("s_waitcnt vmcnt(0)" ::: "memory");
      __builtin_amdgcn_s_barrier();
    }
  }

#pragma unroll
  for (int nt = 0; nt < 4; ++nt) {
    const int n = n0 + wn + nt * 16 + fr;
    const float bb = bias[n];
#pragma unroll
    for (int mt = 0; mt < 4; ++mt) {
      const int mb = m0 + wm + mt * 16 + fq * 4;
      f32x4 a = acc[mt][nt];
#pragma unroll
      for (int r = 0; r < 4; ++r) {
        int m = mb + r;
        Cout[(size_t)m * DM_ + n] = a[r] + bb;
      }
    }
  }
}

// ============== one-shot: x and all 4 weights -> fp16 (RNE) =================
// chunks: x = 2,097,152 float4; each W = 65,536 float4. total 2,359,296.
__global__ __launch_bounds__(256)
void split_all(const float* __restrict__ x,  const float* __restrict__ Wq,
               const float* __restrict__ Wk, const float* __restrict__ Wv,
               const float* __restrict__ Wo,
               unsigned short* __restrict__ xh,
               unsigned short* __restrict__ Wqkvh, unsigned short* __restrict__ Woh)
{
  int i = blockIdx.x * 256 + threadIdx.x;
  const float* src; unsigned short* dh; int off;
  if (i < 2097152) { src = x; dh = xh; off = i; }
  else {
    int j = i - 2097152; int seg = j >> 16; off = j & 65535;
    if (seg == 0)      { src = Wq; dh = Wqkvh; }
    else if (seg == 1) { src = Wk; dh = Wqkvh + 262144; }
    else if (seg == 2) { src = Wv; dh = Wqkvh + 524288; }
    else               { src = Wo; dh = Woh; }
  }
  float4 v = ((const float4*)src)[off];
  ushort4 h;
  h.x = f2h(v.x); h.y = f2h(v.y); h.z = f2h(v.z); h.w = f2h(v.w);
  ((ushort4*)dh)[off] = h;
}

// ==================== FFT: radix-16 Stockham, N=4096, 3 stages ==============
#define FPAD(a) ((a) + ((a) >> 4))
#define LDSN 4352

__device__ __forceinline__ float2 cmul(float2 a, float2 b) {
  return make_float2(a.x * b.x - a.y * b.y, a.x * b.y + a.y * b.x);
}

__device__ __forceinline__ void dft16(float2* x)
{
  const float C1 = 0.9238795325112867f, S1 = 0.3826834323650898f;
  const float C2 = 0.7071067811865476f;
  const float2 w16[16] = {
    { 1.f, 0.f}, { C1,-S1}, { C2,-C2}, { S1,-C1},
    { 0.f,-1.f}, {-S1,-C1}, {-C2,-C2}, {-C1,-S1},
    {-1.f, 0.f}, {-C1, S1}, {-C2, C2}, {-S1, C1},
    { 0.f, 1.f}, { S1, C1}, { C2, C2}, { C1, S1}};
  float2 y[16];
#pragma unroll
  for (int jj = 0; jj < 4; jj++) {
    float2 a = x[jj], b = x[jj + 4], c = x[jj + 8], d = x[jj + 12];
    float2 t0 = make_float2(a.x + c.x, a.y + c.y);
    float2 t1 = make_float2(a.x - c.x, a.y - c.y);
    float2 t2 = make_float2(b.x + d.x, b.y + d.y);
    float2 t3 = make_float2(b.x - d.x, b.y - d.y);
    float2 u0 = make_float2(t0.x + t2.x, t0.y + t2.y);
    float2 u2 = make_float2(t0.x - t2.x, t0.y - t2.y);
    float2 u1 = make_float2(t1.x + t3.y, t1.y - t3.x);
    float2 u3 = make_float2(t1.x - t3.y, t1.y + t3.x);
    y[4 * jj + 0] = u0;
    y[4 * jj + 1] = cmul(u1, w16[(jj * 1) & 15]);
    y[4 * jj + 2] = cmul(u2, w16[(jj * 2) & 15]);
    y[4 * jj + 3] = cmul(u3, w16[(jj * 3) & 15]);
  }
#pragma unroll
  for (int jj = 0; jj < 4; jj++) {
    float2 a = y[jj], b = y[jj + 4], c = y[jj + 8], d = y[jj + 12];
    float2 t0 = make_float2(a.x + c.x, a.y + c.y);
    float2 t1 = make_float2(a.x - c.x, a.y - c.y);
    float2 t2 = make_float2(b.x + d.x, b.y + d.y);
    float2 t3 = make_float2(b.x - d.x, b.y - d.y);
    x[jj + 0]  = make_float2(t0.x + t2.x, t0.y + t2.y);
    x[jj + 8]  = make_float2(t0.x - t2.x, t0.y - t2.y);
    x[jj + 4]  = make_float2(t1.x + t3.y, t1.y - t3.x);
    x[jj + 12] = make_float2(t1.x - t3.y, t1.y + t3.x);
  }
}

// stage 1 from registers: x[r] = z[j + 256r]; writes padded stage-1 output.
__device__ __forceinline__ void fft_stage1_reg(float2* x, float2* __restrict__ Ys, int j)
{
  dft16(x);
  float ang = -1.5339807878856412e-3f * (float)j;   // -2*pi/4096 * j
  float2 w; __sincosf(ang, &w.y, &w.x);
  float2 t = w;
#pragma unroll
  for (int k = 1; k < 16; k++) { x[k] = cmul(x[k], t); t = cmul(t, w); }
  float2* yp = Ys + 17 * j;                         // FPAD(16j+k) = 17j+k
#pragma unroll
  for (int k = 0; k < 16; k++) yp[k] = x[k];
}

template<int S, bool PADOUT>
__device__ __forceinline__ void fft_stage(const float2* __restrict__ Xs,
                                          float2* __restrict__ Ys, int j)
{
  float2 x[16];
#pragma unroll
  for (int r = 0; r < 16; r++) { int a = j + 256 * r; x[r] = Xs[FPAD(a)]; }
  dft16(x);
  if (S < 256) {
    int p = (S == 1) ? j : (j >> 4);
    float ang = -1.5339807878856412e-3f * (float)(p * S);
    float2 w; __sincosf(ang, &w.y, &w.x);
    float2 t = w;
#pragma unroll
    for (int k = 1; k < 16; k++) { x[k] = cmul(x[k], t); t = cmul(t, w); }
  }
  const int q = j & (S - 1);
  const int base = q + ((j - q) << 4);   // q + 16*p*S
#pragma unroll
  for (int k = 0; k < 16; k++) {
    int a = base + k * S;
    Ys[PADOUT ? FPAD(a) : a] = x[k];
  }
}

// One workgroup per (b*H+h, d-group of 4). grid (32, 16). Q,K in fp16.
// Next channel's loads are issued right after stage1 consumes x (T14 split),
// hiding HBM latency under stages 2-3 + unpack.
__global__ __launch_bounds__(256)
void fft_fwd_kernel(const unsigned short* __restrict__ Qh,
                    const unsigned short* __restrict__ Kh,
                    float* __restrict__ P)
{
  __shared__ __attribute__((aligned(16))) float2 Abuf[LDSN];
  __shared__ __attribute__((aligned(16))) float2 Bbuf[LDSN];
  const int tid = threadIdx.x;
  const int bh = blockIdx.x;      // 0..31
  const int g  = blockIdx.y;      // 0..15
  float2 accv[16];
#pragma unroll
  for (int r = 0; r < 16; r++) accv[r] = make_float2(0.f, 0.f);

  const unsigned short* qb = Qh + (size_t)bh * DK_ * L_;
  const unsigned short* kb = Kh + (size_t)bh * DK_ * L_;

  float2 x[16];
  {
    const unsigned short* q = qb + (size_t)(g * 4) * L_;
    const unsigned short* k = kb + (size_t)(g * 4) * L_;
#pragma unroll
    for (int r = 0; r < 16; r++) {
      int t = tid + 256 * r;
      x[r] = make_float2(h2f(q[t]), h2f(k[t]));   // z = q + i*k
    }
  }

  for (int dd = 0; dd < 4; dd++) {
    __syncthreads();               // prev channel's unpack reads of Abuf done
    fft_stage1_reg(x, Abuf, tid);  // consumes x
    if (dd < 3) {                  // prefetch next channel under stages 2-3
      const unsigned short* q = qb + (size_t)(g * 4 + dd + 1) * L_;
      const unsigned short* k = kb + (size_t)(g * 4 + dd + 1) * L_;
#pragma unroll
      for (int r = 0; r < 16; r++) {
        int t = tid + 256 * r;
        x[r] = make_float2(h2f(q[t]), h2f(k[t]));
      }
    }
    __syncthreads();
    fft_stage<16, true>(Abuf, Bbuf, tid);
    __syncthreads();
    fft_stage<256, false>(Bbuf, Abuf, tid);   // result in Abuf, unpadded
    __syncthreads();
#pragma unroll
    for (int r = 0; r < 16; r++) {
      int f = tid + 256 * r;
      float2 zf = Abuf[f];
      float2 zc = Abuf[(L_ - f) & (L_ - 1)];
      float qr = 0.5f * (zf.x + zc.x);       // Qf = (Z[f]+conj(Z[N-f]))/2
      float qi = 0.5f * (zf.y - zc.y);
      float kr = 0.5f * (zf.y + zc.y);       // Kf = (Z[f]-conj(Z[N-f]))/(2i)
      float ki = 0.5f * (zc.x - zf.x);
      accv[r].x += qr * kr + qi * ki;        // G = Qf * conj(Kf)
      accv[r].y += qi * kr - qr * ki;
    }
  }
  float2* Pp = (float2*)P + ((size_t)bh * NPART + g) * L_;
#pragma unroll
  for (int r = 0; r < 16; r++) Pp[tid + 256 * r] = accv[r];
}

// ====== reduce 16 partial spectra -> conjugated spectrum S (HBM stream) =====
__global__ __launch_bounds__(256)
void reduce_partials(const float* __restrict__ P, float* __restrict__ S)
{
  const int bh = blockIdx.x;
  const int c  = blockIdx.y * 256 + threadIdx.x;   // 0..2047 float4 chunks
  const float4* Pp4 = (const float4*)P + (size_t)bh * NPART * 2048 + c;
  float4 s = make_float4(0.f, 0.f, 0.f, 0.f);
#pragma unroll
  for (int g = 0; g < NPART; g++) {
    float4 v = Pp4[(size_t)g * 2048];
    s.x += v.x; s.y += v.y; s.z += v.z; s.w += v.w;
  }
  ((float4*)S)[(size_t)bh * 2048 + c] = make_float4(s.x, -s.y, s.z, -s.w);  // conj
}

// ================= fused: inverse FFT of S + top-16 + softmax ===============
// Top-16 runs FROM LDS (rule #20). __launch_bounds__(256, 1): 32 blocks /
// 70 KB LDS -> never more than 1 block/CU; full register budget avoids the
// spill knife-edge (rule #19).
__global__ __launch_bounds__(256, 1)
void fft_inv_topk_kernel(const float* __restrict__ S, float* __restrict__ w,
                         int* __restrict__ delays)
{
  __shared__ __attribute__((aligned(16))) float2 Abuf[LDSN];
  __shared__ __attribute__((aligned(16))) float2 Bbuf[LDSN];
  __shared__ float wtv[64];
  __shared__ int   wti[64];
  const int tid = threadIdx.x;
  const int lane = tid & 63, wave = tid >> 6;
  const int bh = blockIdx.x;
  const float2* Sp = (const float2*)S + (size_t)bh * L_;

  float2 x[16];
#pragma unroll
  for (int r = 0; r < 16; r++) x[r] = Sp[tid + 256 * r];
  fft_stage1_reg(x, Abuf, tid);
  __syncthreads();
  fft_stage<16, true>(Abuf, Bbuf, tid);
  __syncthreads();
  fft_stage<256, false>(Bbuf, Abuf, tid);   // result in Abuf, unpadded
  __syncthreads();

  const float scale = 1.0f / ((float)L_ * (float)DK_);

  // phase A: per-wave top-16, values read from LDS each pass, shuffle argmax.
  for (int it = 0; it < TOPK; it++) {
    float lbv = -INFINITY; int lbi = 0;
#pragma unroll
    for (int r = 0; r < 16; r++) {
      float val = Abuf[tid + 256 * r].x;
      if (val > lbv) { lbv = val; lbi = tid + 256 * r; }
    }
    float bv = lbv; int bi = lbi;
#pragma unroll
    for (int off = 32; off > 0; off >>= 1) {
      float ov = __shfl_down(bv, off, 64);
      int   oi = __shfl_down(bi, off, 64);
      if (ov > bv || (ov == bv && oi < bi)) { bv = ov; bi = oi; }
    }
    const float wv = __shfl(bv, 0, 64);
    const int   wi = __shfl(bi, 0, 64);
    if (lane == 0) {
      wtv[wave * TOPK + it] = wv * scale;
      wti[wave * TOPK + it] = wi;
      Abuf[wi].x = -INFINITY;               // disable (own wave's region only)
    }
  }
  __syncthreads();

  // phase B: wave 0 merges 4x16 candidates -> global top-16 + softmax
  if (wave == 0) {
    float cv = wtv[lane]; int ci = wti[lane];
    float topv[TOPK]; int topi[TOPK];
#pragma unroll
    for (int it = 0; it < TOPK; it++) {
      float bv = cv; int bi = ci;
#pragma unroll
      for (int off = 1; off < 64; off <<= 1) {
        float ov = __shfl_xor(bv, off, 64);
        int   oi = __shfl_xor(bi, off, 64);
        if (ov > bv || (ov == bv && oi < bi)) { bv = ov; bi = oi; }
      }
      topv[it] = bv; topi[it] = bi;         // all lanes hold the winner
      if (ci == bi) cv = -INFINITY;         // exactly one lane matches
    }
    if (lane == 0) {
      float mx = topv[0];
#pragma unroll
      for (int j = 1; j < TOPK; j++) mx = fmaxf(mx, topv[j]);
      float e[TOPK]; float se = 0.f;
#pragma unroll
      for (int j = 0; j < TOPK; j++) { e[j] = expf(topv[j] - mx); se += e[j]; }
      float inv = 1.0f / se;
#pragma unroll
      for (int j = 0; j < TOPK; j++) {
        w[bh * TOPK + j] = e[j] * inv;
        delays[bh * TOPK + j] = topi[j];
      }
    }
  }
}

// ============================ delay gather ==================================
// V fp16 [b][h][t][d] -> ctx fp16 (RNE) [b][t][h*64+d]
// Flat grid 4096, XCD-affine: xcd = id&7 handles bh in [4*xcd, 4*xcd+4), so
// each XCD's V working set (~2 MB/bh) stays L2-resident across its blocks.
// 16B loads (f16x8), 32 t-rows per block.
__global__ __launch_bounds__(256)
void gather_kernel(const unsigned short* __restrict__ V, const float* __restrict__ w,
                   const int* __restrict__ delays, unsigned short* __restrict__ ctxh)
{
  const int id  = blockIdx.x;          // 0..4095
  const int xcd = id & 7;
  const int j   = id >> 3;             // 0..511
  const int bh  = xcd * 4 + (j >> 7);  // 4 bh per XCD, sequential within
  const int tb  = j & 127;             // t-block of 32 rows
  const int b = bh >> 3, h = bh & 7;
  __shared__ float ws[TOPK];
  __shared__ int   dls[TOPK];
  const int tid = threadIdx.x;
  if (tid < TOPK) { ws[tid] = w[bh * TOPK + tid]; dls[tid] = delays[bh * TOPK + tid]; }
  __syncthreads();
  const int t  = tb * 32 + (tid >> 3);
  const int d8 = (tid & 7) * 8;
  const unsigned short* Vh = V + (size_t)bh * L_ * DK_;
  float acc[8];
#pragma unroll
  for (int e = 0; e < 8; e++) acc[e] = 0.f;
#pragma unroll
  for (int jj = 0; jj < TOPK; jj++) {
    int row = (t - dls[jj]) & (L_ - 1);
    f16x8 vv = *(const f16x8*)(Vh + (size_t)row * DK_ + d8);
    float wj = ws[jj];
#pragma unroll
    for (int e = 0; e < 8; e++) acc[e] += wj * (float)vv[e];
  }
  f16x8 hv;
#pragma unroll
  for (int e = 0; e < 8; e++) hv[e] = (_Float16)acc[e];
  *(f16x8*)(ctxh + ((size_t)(b * L_ + t) * DM_) + h * DK_ + d8) = hv;
}

// ============================ launch ========================================
extern "C" void kernel_launch(void* const* d_in, const int* in_sizes, int n_in,
                              void* d_out, int out_size, void* d_ws, size_t ws_size,
                              hipStream_t stream)
{
  const float* x  = (const float*)d_in[0];
  const float* Wq = (const float*)d_in[1];
  const float* bq = (const float*)d_in[2];
  const float* Wk = (const float*)d_in[3];
  const float* bk = (const float*)d_in[4];
  const float* Wv = (const float*)d_in[5];
  const float* bv = (const float*)d_in[6];
  const float* Wo = (const float*)d_in[7];
  const float* bo = (const float*)d_in[8];
  float* out = (float*)d_out;
  float* ws  = (float*)d_ws;

  // workspace (float offsets).
  // region0 [0, 8388608): xh fp16 (split..qkv), then P (fft partials, 16 MB),
  //                       then ctxh fp16 (gather..o_gemm)
  unsigned short* xh = (unsigned short*)ws;                 // 8.4M fp16 (16 MB)
  float* P  = ws;                                           // 32*16*4096*2 f (16 MB)
  unsigned short* ctxh = (unsigned short*)ws;               // 8.4M fp16
  unsigned short* Qh = (unsigned short*)(ws + 8388608);     // 8.4M fp16 [b][h][d][t]
  unsigned short* Kh = (unsigned short*)(ws + 12582912);    // 8.4M fp16 [b][h][d][t]
  unsigned short* Vv = (unsigned short*)(ws + 16777216);    // 8.4M fp16 [b][h][t][d]
  unsigned short* Wqkvh = (unsigned short*)(ws + 20971520); // 786,432 fp16
  unsigned short* Woh   = (unsigned short*)(ws + 21364736); // 262,144 fp16
  float* wbuf = ws + 21495808;                              // 512
  int*   dbuf = (int*)(ws + 21496320);                      // 512
  float* S    = ws + 21496832;                              // 262,144 f (1 MB)

  split_all<<<9216, 256, 0, stream>>>(x, Wq, Wk, Wv, Wo, xh, Wqkvh, Woh);

  qkv_gemm<<<1536, 256, 0, stream>>>(xh, Wqkvh, bq, bk, bv, Qh, Kh, Vv);

  fft_fwd_kernel<<<dim3(32, NPART), 256, 0, stream>>>(Qh, Kh, P);
  reduce_partials<<<dim3(32, 8), 256, 0, stream>>>(P, S);
  fft_inv_topk_kernel<<<32, 256, 0, stream>>>(S, wbuf, dbuf);
  gather_kernel<<<4096, 256, 0, stream>>>(Vv, wbuf, dbuf, ctxh);

  o_gemm<<<512, 256, 0, stream>>>(ctxh, Woh, bo, out);
}